// Round 5
// baseline (35.478 us; speedup 1.0000x reference)
//
#include <hip/hip_runtime.h>

#define NCH   85   // 80 cls + 4 bbox + 1 ctr
#define TILE  64   // positions per block
#define LS    67   // LDS row stride: 67%32=3, odd -> conflict-free A-writes and C-reads
#define OUTCH 87   // 2 coord + 80 scores + 4 bbox + 1 ctr
#define NF4   1392 // TILE*OUTCH/4 float4s per block

typedef float f32x4 __attribute__((ext_vector_type(4)));  // NT-store-compatible

__global__ __launch_bounds__(256) void fcos_filter_kernel(
    const float* __restrict__ c0, const float* __restrict__ b0, const float* __restrict__ t0,
    const float* __restrict__ c1, const float* __restrict__ b1, const float* __restrict__ t1,
    const float* __restrict__ c2, const float* __restrict__ b2, const float* __restrict__ t2,
    const float* __restrict__ c3, const float* __restrict__ b3, const float* __restrict__ t3,
    const float* __restrict__ c4, const float* __restrict__ b4, const float* __restrict__ t4,
    float* __restrict__ out)
{
    __shared__ float lds[NCH * LS];   // 85*67*4 = 22,780 B
    __shared__ float s_flag[TILE];    // +256 B -> 7 blocks/CU

    const int bid = blockIdx.x;
    const int tid = threadIdx.x;

    // ---- level decode ----
    const float *cls, *bbx, *ctr;
    int img, tile, HW, W, str, ksh;
    size_t obase;
    if (bid < 3200)      { cls=c0; bbx=b0; ctr=t0; HW=25600; W=160; str=8;   ksh=4; obase=0u;
                           img = bid / 400;          tile = bid - img * 400; }
    else if (bid < 4000) { cls=c1; bbx=b1; ctr=t1; HW=6400;  W=80;  str=16;  ksh=3; obase=17817600u;
                           const int bl = bid - 3200; img = bl / 100; tile = bl - img * 100; }
    else if (bid < 4200) { cls=c2; bbx=b2; ctr=t2; HW=1600;  W=40;  str=32;  ksh=2; obase=22272000u;
                           const int bl = bid - 4000; img = bl / 25;  tile = bl - img * 25; }
    else if (bid < 4256) { cls=c3; bbx=b3; ctr=t3; HW=400;   W=20;  str=64;  ksh=1; obase=23385600u;
                           const int bl = bid - 4200; img = bl / 7;   tile = bl - img * 7; }
    else                 { cls=c4; bbx=b4; ctr=t4; HW=100;   W=10;  str=128; ksh=0; obase=23664000u;
                           const int bl = bid - 4256; img = bl >> 1;  tile = bl & 1; }

    const int p0    = tile * TILE;
    const int valid = min(TILE, HW - p0);   // <64 only in level 3/4 tail blocks

    // ---- Phase A: global -> LDS; per-thread cls max in registers ----
    const int  lane_c = tid >> 4;           // 0..15
    const int  q4     = (tid & 15) << 2;    // 0,4,...,60
    const bool qok    = q4 < valid;

    float4 v0, v1, v2, v3, v4, v5;
    float4 fm = make_float4(-1e30f, -1e30f, -1e30f, -1e30f);
    const float* abase = cls + ((size_t)img * 80 + lane_c) * HW + p0 + q4;
    if (qok) {
        v0 = *reinterpret_cast<const float4*>(abase);
        v1 = *reinterpret_cast<const float4*>(abase + (size_t)16 * HW);
        v2 = *reinterpret_cast<const float4*>(abase + (size_t)32 * HW);
        v3 = *reinterpret_cast<const float4*>(abase + (size_t)48 * HW);
        v4 = *reinterpret_cast<const float4*>(abase + (size_t)64 * HW);
        fm.x = fmaxf(fmaxf(fmaxf(v0.x, v1.x), fmaxf(v2.x, v3.x)), v4.x);
        fm.y = fmaxf(fmaxf(fmaxf(v0.y, v1.y), fmaxf(v2.y, v3.y)), v4.y);
        fm.z = fmaxf(fmaxf(fmaxf(v0.z, v1.z), fmaxf(v2.z, v3.z)), v4.z);
        fm.w = fmaxf(fmaxf(fmaxf(v0.w, v1.w), fmaxf(v2.w, v3.w)), v4.w);
    }
    const bool r5 = (tid < 80) && qok;      // channels 80..84 (bbox, ctr)
    if (r5) {
        const float* s5 = (lane_c < 4)
            ? bbx + ((size_t)img * 4 + lane_c) * HW + p0 + q4
            : ctr + (size_t)img * HW + p0 + q4;
        v5 = *reinterpret_cast<const float4*>(s5);
    }

    #define PUT(base_c, V)                                          \
    {   const int a = (base_c + lane_c) * LS + q4;                  \
        lds[a + 0] = V.x; lds[a + 1] = V.y;                         \
        lds[a + 2] = V.z; lds[a + 3] = V.w;                         \
    }
    if (qok) { PUT(0, v0) PUT(16, v1) PUT(32, v2) PUT(48, v3) PUT(64, v4) }
    if (r5)  { PUT(80, v5) }
    #undef PUT

    // wave-level reduce of fm across the 4 lane_c groups in this wave
    fm.x = fmaxf(fm.x, __shfl_xor(fm.x, 16));
    fm.y = fmaxf(fm.y, __shfl_xor(fm.y, 16));
    fm.z = fmaxf(fm.z, __shfl_xor(fm.z, 16));
    fm.w = fmaxf(fm.w, __shfl_xor(fm.w, 16));
    fm.x = fmaxf(fm.x, __shfl_xor(fm.x, 32));
    fm.y = fmaxf(fm.y, __shfl_xor(fm.y, 32));
    fm.z = fmaxf(fm.z, __shfl_xor(fm.z, 32));
    fm.w = fmaxf(fm.w, __shfl_xor(fm.w, 32));

    if (tid < TILE) s_flag[tid] = 0.0f;     // before barrier1: safe vs flag writes
    __syncthreads();

    // one set of flag writers per wave (lanes 0..15), cross-wave OR via same-addr stores
    if ((tid & 63) < 16) {
        if (fm.x > 0.5f) s_flag[q4 + 0] = 1.0f;
        if (fm.y > 0.5f) s_flag[q4 + 1] = 1.0f;
        if (fm.z > 0.5f) s_flag[q4 + 2] = 1.0f;
        if (fm.w > 0.5f) s_flag[q4 + 3] = 1.0f;
    }
    __syncthreads();

    // ---- Phase C: LDS -> global, float4 NT stores over the contiguous chunk ----
    float* dst = out + obase + ((size_t)img * HW + p0) * OUTCH;
    const int nmax = valid * OUTCH;
    #pragma unroll
    for (int r = 0; r < 6; ++r) {
        const int f4 = tid + 256 * r;
        if (r == 5 && f4 >= NF4) break;
        const int e0 = f4 * 4;
        if (e0 >= nmax) break;
        const int p  = e0 / OUTCH;          // magic-mul div
        const int ch = e0 - p * OUTCH;
        float vals[4];
        #pragma unroll
        for (int j = 0; j < 4; ++j) {
            int chj = ch + j, pj = p;
            if (chj >= OUTCH) { chj -= OUTCH; pj += 1; }
            const float m = s_flag[pj];
            float val;
            if (chj >= 2) {
                val = lds[(chj - 2) * LS + pj] * m;
            } else {
                const int pg = p0 + pj;
                const int t  = pg >> ksh;   // = pg / (W/10)
                const int y  = t / 10;      // magic-mul div by 10
                const int x  = pg - y * W;
                const int coord = (chj == 0) ? x : y;
                val = (float)(coord * str + (str >> 1)) * m;
            }
            vals[j] = val;
        }
        if (e0 + 4 <= nmax) {
            f32x4 o; o.x = vals[0]; o.y = vals[1]; o.z = vals[2]; o.w = vals[3];
            __builtin_nontemporal_store(o, reinterpret_cast<f32x4*>(dst + e0));
        } else {                             // ragged tail (level 3/4 edge blocks only)
            #pragma unroll
            for (int j = 0; j < 4; ++j)
                if (e0 + j < nmax) __builtin_nontemporal_store(vals[j], dst + e0 + j);
        }
    }
}

extern "C" void kernel_launch(void* const* d_in, const int* in_sizes, int n_in,
                              void* d_out, int out_size, void* d_ws, size_t ws_size,
                              hipStream_t stream) {
    (void)in_sizes; (void)n_in; (void)out_size; (void)d_ws; (void)ws_size;
    fcos_filter_kernel<<<4272, 256, 0, stream>>>(
        (const float*)d_in[0],  (const float*)d_in[1],  (const float*)d_in[2],
        (const float*)d_in[3],  (const float*)d_in[4],  (const float*)d_in[5],
        (const float*)d_in[6],  (const float*)d_in[7],  (const float*)d_in[8],
        (const float*)d_in[9],  (const float*)d_in[10], (const float*)d_in[11],
        (const float*)d_in[12], (const float*)d_in[13], (const float*)d_in[14],
        (float*)d_out);
}